// Round 8
// baseline (21.428 us; speedup 1.0000x reference)
//
#include <hip/hip_runtime.h>

// BiorUpSampling: 2x zero-interleaved upsample + separable symmetric 9-tap
// filter, SAME zero padding. Polyphase, register-streaming 5-row ring with a
// 1-deep explicit load pipeline. RP=8, plain (cacheable) stores: the full
// working set (64MB out + 16MB in) fits in the 256MB Infinity Cache, so
// letting writes allocate in L2/L3 should lift the ceiling above HBM write BW.

constexpr int H = 512, W = 512;
constexpr int RP = 8;   // input rows advanced per block -> 16 output rows

typedef float f32x4 __attribute__((ext_vector_type(4)));

__global__ __launch_bounds__(256)
void bior_up_kernel(const float* __restrict__ in, float* __restrict__ out) {
  constexpr float E0 =  0.03782845550699535f;
  constexpr float E1 = -0.1106244044184226f;
  constexpr float E2 =  0.8526986790094022f;
  constexpr float E3 = -0.1106244044184226f;
  constexpr float E4 =  0.03782845550699535f;
  constexpr float O0 = -0.02384946501937986f;
  constexpr float O1 =  0.3774028556126536f;
  constexpr float O2 =  0.3774028556126537f;
  constexpr float O3 = -0.02384946501937986f;

  const int tid = threadIdx.x;
  const int r0  = blockIdx.x * RP;
  const int b   = blockIdx.y;
  const float* inb  = in  + (size_t)b * H * W;
  float*       outb = out + (size_t)b * (2 * H) * (2 * W);

  const int c = 2 * tid;              // this thread's input cols: c, c+1
  const bool lv = (c >= 2);
  const bool rv = (c <= W - 4);

  auto loadrow = [&](int gr, float2& L, float2& M, float2& R) {
    const bool rowv = ((unsigned)gr < (unsigned)H);
    const float* rowp = inb + (size_t)gr * W;
    const float2 z = make_float2(0.0f, 0.0f);
    L = (rowv && lv) ? *reinterpret_cast<const float2*>(rowp + c - 2) : z;
    M =  rowv        ? *reinterpret_cast<const float2*>(rowp + c)     : z;
    R = (rowv && rv) ? *reinterpret_cast<const float2*>(rowp + c + 2) : z;
  };
  auto hfilt = [&](float2 L, float2 M, float2 R,
                   float& a, float& bb, float& cc, float& dd) {
    const float v0 = L.x, v1 = L.y, v2 = M.x, v3 = M.y, v4 = R.x, v5 = R.y;
    a  = v0*E0 + v1*E1 + v2*E2 + v3*E3 + v4*E4;   // he(c)   -> out col 2c
    bb = v1*O0 + v2*O1 + v3*O2 + v4*O3;           // ho(c)   -> out col 2c+1
    cc = v1*E0 + v2*E1 + v3*E2 + v4*E3 + v5*E4;   // he(c+1) -> out col 2c+2
    dd = v2*O0 + v3*O1 + v4*O2 + v5*O3;           // ho(c+1) -> out col 2c+3
  };

  // Ring of horizontally-filtered rows; slot k holds row (center-2+k).
  float A[5], B[5], C[5], D[5];

  // Prologue: issue all 5 lead-in row loads back-to-back, then compute.
  float2 La, Ma, Ra, Lb, Mb, Rb, Lc, Mc, Rc, Ld, Md, Rd;
  float2 L0, M0, R0, L1, M1, R1;
  loadrow(r0 - 2, La, Ma, Ra);
  loadrow(r0 - 1, Lb, Mb, Rb);
  loadrow(r0    , Lc, Mc, Rc);
  loadrow(r0 + 1, Ld, Md, Rd);
  loadrow(r0 + 2, L0, M0, R0);   // first main-loop row, preloaded
  hfilt(La, Ma, Ra, A[0], B[0], C[0], D[0]);
  hfilt(Lb, Mb, Rb, A[1], B[1], C[1], D[1]);
  hfilt(Lc, Mc, Rc, A[2], B[2], C[2], D[2]);
  hfilt(Ld, Md, Rd, A[3], B[3], C[3], D[3]);

#pragma unroll
  for (int p = 0; p < RP; ++p) {
    if (p + 1 < RP) loadrow(r0 + 3 + p, L1, M1, R1);   // prefetch next row

    hfilt(L0, M0, R0, A[4], B[4], C[4], D[4]);         // consume preloaded row

    f32x4 ev, od;
    ev.x = A[0]*E0 + A[1]*E1 + A[2]*E2 + A[3]*E3 + A[4]*E4;
    ev.y = B[0]*E0 + B[1]*E1 + B[2]*E2 + B[3]*E3 + B[4]*E4;
    ev.z = C[0]*E0 + C[1]*E1 + C[2]*E2 + C[3]*E3 + C[4]*E4;
    ev.w = D[0]*E0 + D[1]*E1 + D[2]*E2 + D[3]*E3 + D[4]*E4;
    od.x = A[1]*O0 + A[2]*O1 + A[3]*O2 + A[4]*O3;
    od.y = B[1]*O0 + B[2]*O1 + B[3]*O2 + B[4]*O3;
    od.z = C[1]*O0 + C[2]*O1 + C[3]*O2 + C[4]*O3;
    od.w = D[1]*O0 + D[2]*O1 + D[3]*O2 + D[4]*O3;

    const int row_e = 2 * (r0 + p);
    *reinterpret_cast<f32x4*>(&outb[(size_t)row_e       * (2 * W) + 4 * tid]) = ev;
    *reinterpret_cast<f32x4*>(&outb[(size_t)(row_e + 1) * (2 * W) + 4 * tid]) = od;

#pragma unroll
    for (int k = 0; k < 4; ++k) {
      A[k] = A[k + 1]; B[k] = B[k + 1]; C[k] = C[k + 1]; D[k] = D[k + 1];
    }
    L0 = L1; M0 = M1; R0 = R1;
  }
}

extern "C" void kernel_launch(void* const* d_in, const int* in_sizes, int n_in,
                              void* d_out, int out_size, void* d_ws, size_t ws_size,
                              hipStream_t stream) {
  const float* in = (const float*)d_in[0];
  float* out = (float*)d_out;
  const int batch = in_sizes[0] / (H * W);
  dim3 grid(H / RP, batch);   // 64 x 16 = 1024 blocks -> 4 blocks/CU
  bior_up_kernel<<<grid, 256, 0, stream>>>(in, out);
}

// Round 9
// 20.430 us; speedup vs baseline: 1.0489x; 1.0489x over previous
//
#include <hip/hip_runtime.h>

// BiorUpSampling: 2x zero-interleaved upsample + separable symmetric 9-tap
// filter, SAME zero padding. Polyphase, register-streaming 5-row ring,
// 1-deep load prefetch, NT stores (write-once output, bypass L2 alloc).
// XCD-aware block swizzle: flat ids round-robin over 8 XCDs, so
// new_flat = (flat%8)*128 + flat/8 gives each XCD a contiguous 128-block
// chunk = 2 batches (~2.1MB input) -> resident in its private 4MB L2.

constexpr int H = 512, W = 512;
constexpr int RP = 8;   // input rows advanced per block -> 16 output rows
constexpr int TILES_X = H / RP;   // 64 row-tiles per batch

typedef float f32x4 __attribute__((ext_vector_type(4)));

__global__ __launch_bounds__(256)
void bior_up_kernel(const float* __restrict__ in, float* __restrict__ out,
                    int nblocks) {
  constexpr float E0 =  0.03782845550699535f;
  constexpr float E1 = -0.1106244044184226f;
  constexpr float E2 =  0.8526986790094022f;
  constexpr float E3 = -0.1106244044184226f;
  constexpr float E4 =  0.03782845550699535f;
  constexpr float O0 = -0.02384946501937986f;
  constexpr float O1 =  0.3774028556126536f;
  constexpr float O2 =  0.3774028556126537f;
  constexpr float O3 = -0.02384946501937986f;

  // XCD swizzle (bijective: nblocks % 8 == 0): XCD k gets a contiguous
  // chunk of work = 2 batches, vertically-adjacent tiles stay on-XCD.
  const int flat = blockIdx.x;
  const int cpx  = nblocks >> 3;                    // blocks per XCD chunk
  const int nf   = (flat & 7) * cpx + (flat >> 3);  // swizzled flat id
  const int tile = nf & (TILES_X - 1);
  const int b    = nf / TILES_X;

  const int tid = threadIdx.x;
  const int r0  = tile * RP;
  const float* inb  = in  + (size_t)b * H * W;
  float*       outb = out + (size_t)b * (2 * H) * (2 * W);

  const int c = 2 * tid;              // this thread's input cols: c, c+1
  const bool lv = (c >= 2);
  const bool rv = (c <= W - 4);

  auto loadrow = [&](int gr, float2& L, float2& M, float2& R) {
    const bool rowv = ((unsigned)gr < (unsigned)H);
    const float* rowp = inb + (size_t)gr * W;
    const float2 z = make_float2(0.0f, 0.0f);
    L = (rowv && lv) ? *reinterpret_cast<const float2*>(rowp + c - 2) : z;
    M =  rowv        ? *reinterpret_cast<const float2*>(rowp + c)     : z;
    R = (rowv && rv) ? *reinterpret_cast<const float2*>(rowp + c + 2) : z;
  };
  auto hfilt = [&](float2 L, float2 M, float2 R,
                   float& a, float& bb, float& cc, float& dd) {
    const float v0 = L.x, v1 = L.y, v2 = M.x, v3 = M.y, v4 = R.x, v5 = R.y;
    a  = v0*E0 + v1*E1 + v2*E2 + v3*E3 + v4*E4;   // he(c)   -> out col 2c
    bb = v1*O0 + v2*O1 + v3*O2 + v4*O3;           // ho(c)   -> out col 2c+1
    cc = v1*E0 + v2*E1 + v3*E2 + v4*E3 + v5*E4;   // he(c+1) -> out col 2c+2
    dd = v2*O0 + v3*O1 + v4*O2 + v5*O3;           // ho(c+1) -> out col 2c+3
  };

  // Ring of horizontally-filtered rows; slot k holds row (center-2+k).
  float A[5], B[5], C[5], D[5];

  // Prologue: issue all 5 lead-in row loads back-to-back, then compute.
  float2 La, Ma, Ra, Lb, Mb, Rb, Lc, Mc, Rc, Ld, Md, Rd;
  float2 L0, M0, R0, L1, M1, R1;
  loadrow(r0 - 2, La, Ma, Ra);
  loadrow(r0 - 1, Lb, Mb, Rb);
  loadrow(r0    , Lc, Mc, Rc);
  loadrow(r0 + 1, Ld, Md, Rd);
  loadrow(r0 + 2, L0, M0, R0);   // first main-loop row, preloaded
  hfilt(La, Ma, Ra, A[0], B[0], C[0], D[0]);
  hfilt(Lb, Mb, Rb, A[1], B[1], C[1], D[1]);
  hfilt(Lc, Mc, Rc, A[2], B[2], C[2], D[2]);
  hfilt(Ld, Md, Rd, A[3], B[3], C[3], D[3]);

#pragma unroll
  for (int p = 0; p < RP; ++p) {
    if (p + 1 < RP) loadrow(r0 + 3 + p, L1, M1, R1);   // prefetch next row

    hfilt(L0, M0, R0, A[4], B[4], C[4], D[4]);         // consume preloaded row

    f32x4 ev, od;
    ev.x = A[0]*E0 + A[1]*E1 + A[2]*E2 + A[3]*E3 + A[4]*E4;
    ev.y = B[0]*E0 + B[1]*E1 + B[2]*E2 + B[3]*E3 + B[4]*E4;
    ev.z = C[0]*E0 + C[1]*E1 + C[2]*E2 + C[3]*E3 + C[4]*E4;
    ev.w = D[0]*E0 + D[1]*E1 + D[2]*E2 + D[3]*E3 + D[4]*E4;
    od.x = A[1]*O0 + A[2]*O1 + A[3]*O2 + A[4]*O3;
    od.y = B[1]*O0 + B[2]*O1 + B[3]*O2 + B[4]*O3;
    od.z = C[1]*O0 + C[2]*O1 + C[3]*O2 + C[4]*O3;
    od.w = D[1]*O0 + D[2]*O1 + D[3]*O2 + D[4]*O3;

    const int row_e = 2 * (r0 + p);
    f32x4* pe = reinterpret_cast<f32x4*>(&outb[(size_t)row_e       * (2 * W) + 4 * tid]);
    f32x4* po = reinterpret_cast<f32x4*>(&outb[(size_t)(row_e + 1) * (2 * W) + 4 * tid]);
    __builtin_nontemporal_store(ev, pe);
    __builtin_nontemporal_store(od, po);

#pragma unroll
    for (int k = 0; k < 4; ++k) {
      A[k] = A[k + 1]; B[k] = B[k + 1]; C[k] = C[k + 1]; D[k] = D[k + 1];
    }
    L0 = L1; M0 = M1; R0 = R1;
  }
}

extern "C" void kernel_launch(void* const* d_in, const int* in_sizes, int n_in,
                              void* d_out, int out_size, void* d_ws, size_t ws_size,
                              hipStream_t stream) {
  const float* in = (const float*)d_in[0];
  float* out = (float*)d_out;
  const int batch = in_sizes[0] / (H * W);
  const int nblocks = TILES_X * batch;   // 64 x 16 = 1024, %8 == 0
  bior_up_kernel<<<dim3(nblocks), 256, 0, stream>>>(in, out, nblocks);
}

// Round 10
// 18.979 us; speedup vs baseline: 1.1290x; 1.0764x over previous
//
#include <hip/hip_runtime.h>

// BiorUpSampling: 2x zero-interleaved upsample + separable symmetric 9-tap
// filter, SAME zero padding. Polyphase, register-streaming 5-row ring,
// 2-deep explicit load pipeline (row p+2's loads issued at iter p, consumed
// two iterations later -> load latency covered by ~2 iterations of issue),
// NT stores (write-once output, bypass cache alloc). RP=8, 1024 blocks.

constexpr int H = 512, W = 512;
constexpr int RP = 8;   // input rows advanced per block -> 16 output rows

typedef float f32x4 __attribute__((ext_vector_type(4)));

__global__ __launch_bounds__(256)
void bior_up_kernel(const float* __restrict__ in, float* __restrict__ out) {
  constexpr float E0 =  0.03782845550699535f;
  constexpr float E1 = -0.1106244044184226f;
  constexpr float E2 =  0.8526986790094022f;
  constexpr float E3 = -0.1106244044184226f;
  constexpr float E4 =  0.03782845550699535f;
  constexpr float O0 = -0.02384946501937986f;
  constexpr float O1 =  0.3774028556126536f;
  constexpr float O2 =  0.3774028556126537f;
  constexpr float O3 = -0.02384946501937986f;

  const int tid = threadIdx.x;
  const int r0  = blockIdx.x * RP;
  const int b   = blockIdx.y;
  const float* inb  = in  + (size_t)b * H * W;
  float*       outb = out + (size_t)b * (2 * H) * (2 * W);

  const int c = 2 * tid;              // this thread's input cols: c, c+1
  const bool lv = (c >= 2);
  const bool rv = (c <= W - 4);

  auto loadrow = [&](int gr, float2& L, float2& M, float2& R) {
    const bool rowv = ((unsigned)gr < (unsigned)H);
    const float* rowp = inb + (size_t)gr * W;
    const float2 z = make_float2(0.0f, 0.0f);
    L = (rowv && lv) ? *reinterpret_cast<const float2*>(rowp + c - 2) : z;
    M =  rowv        ? *reinterpret_cast<const float2*>(rowp + c)     : z;
    R = (rowv && rv) ? *reinterpret_cast<const float2*>(rowp + c + 2) : z;
  };
  auto hfilt = [&](float2 L, float2 M, float2 R,
                   float& a, float& bb, float& cc, float& dd) {
    const float v0 = L.x, v1 = L.y, v2 = M.x, v3 = M.y, v4 = R.x, v5 = R.y;
    a  = v0*E0 + v1*E1 + v2*E2 + v3*E3 + v4*E4;   // he(c)   -> out col 2c
    bb = v1*O0 + v2*O1 + v3*O2 + v4*O3;           // ho(c)   -> out col 2c+1
    cc = v1*E0 + v2*E1 + v3*E2 + v4*E3 + v5*E4;   // he(c+1) -> out col 2c+2
    dd = v2*O0 + v3*O1 + v4*O2 + v5*O3;           // ho(c+1) -> out col 2c+3
  };

  // Ring of horizontally-filtered rows; slot k holds row (center-2+k).
  float A[5], B[5], C[5], D[5];

  // Prologue: issue all lead-in row loads back-to-back, then compute.
  float2 La, Ma, Ra, Lb, Mb, Rb, Lc, Mc, Rc, Ld, Md, Rd;
  float2 L0, M0, R0, L1, M1, R1, L2, M2, R2;
  loadrow(r0 - 2, La, Ma, Ra);
  loadrow(r0 - 1, Lb, Mb, Rb);
  loadrow(r0    , Lc, Mc, Rc);
  loadrow(r0 + 1, Ld, Md, Rd);
  loadrow(r0 + 2, L0, M0, R0);   // consumed at p=0
  loadrow(r0 + 3, L1, M1, R1);   // consumed at p=1
  hfilt(La, Ma, Ra, A[0], B[0], C[0], D[0]);
  hfilt(Lb, Mb, Rb, A[1], B[1], C[1], D[1]);
  hfilt(Lc, Mc, Rc, A[2], B[2], C[2], D[2]);
  hfilt(Ld, Md, Rd, A[3], B[3], C[3], D[3]);

#pragma unroll
  for (int p = 0; p < RP; ++p) {
    if (p + 2 < RP) loadrow(r0 + 4 + p, L2, M2, R2);   // 2-deep prefetch

    hfilt(L0, M0, R0, A[4], B[4], C[4], D[4]);         // consume oldest set

    f32x4 ev, od;
    ev.x = A[0]*E0 + A[1]*E1 + A[2]*E2 + A[3]*E3 + A[4]*E4;
    ev.y = B[0]*E0 + B[1]*E1 + B[2]*E2 + B[3]*E3 + B[4]*E4;
    ev.z = C[0]*E0 + C[1]*E1 + C[2]*E2 + C[3]*E3 + C[4]*E4;
    ev.w = D[0]*E0 + D[1]*E1 + D[2]*E2 + D[3]*E3 + D[4]*E4;
    od.x = A[1]*O0 + A[2]*O1 + A[3]*O2 + A[4]*O3;
    od.y = B[1]*O0 + B[2]*O1 + B[3]*O2 + B[4]*O3;
    od.z = C[1]*O0 + C[2]*O1 + C[3]*O2 + C[4]*O3;
    od.w = D[1]*O0 + D[2]*O1 + D[3]*O2 + D[4]*O3;

    const int row_e = 2 * (r0 + p);
    f32x4* pe = reinterpret_cast<f32x4*>(&outb[(size_t)row_e       * (2 * W) + 4 * tid]);
    f32x4* po = reinterpret_cast<f32x4*>(&outb[(size_t)(row_e + 1) * (2 * W) + 4 * tid]);
    __builtin_nontemporal_store(ev, pe);
    __builtin_nontemporal_store(od, po);

#pragma unroll
    for (int k = 0; k < 4; ++k) {
      A[k] = A[k + 1]; B[k] = B[k + 1]; C[k] = C[k + 1]; D[k] = D[k + 1];
    }
    L0 = L1; M0 = M1; R0 = R1;
    L1 = L2; M1 = M2; R1 = R2;
  }
}

extern "C" void kernel_launch(void* const* d_in, const int* in_sizes, int n_in,
                              void* d_out, int out_size, void* d_ws, size_t ws_size,
                              hipStream_t stream) {
  const float* in = (const float*)d_in[0];
  float* out = (float*)d_out;
  const int batch = in_sizes[0] / (H * W);
  dim3 grid(H / RP, batch);   // 64 x 16 = 1024 blocks -> 4 blocks/CU
  bior_up_kernel<<<grid, 256, 0, stream>>>(in, out);
}